// Round 3
// baseline (952.520 us; speedup 1.0000x reference)
//
#include <hip/hip_runtime.h>
#include <cstdio>

// MoE top-2 FFN: B=4,S=2048,D=1024 -> T=8192 tokens; E=8, H=4096, K_TOP=2.
// Round 3: 256x256 8-phase counted-vmcnt grouped GEMMs (T2 swizzle + T3/T4 + T5),
//          GEMM2 epilogue atomicAdds into zeroed out (drops ybuf+combine).

#define T_TOK 8192
#define DIM   1024
#define NEXP  8
#define HID   4096
#define MAXR  18432  // 16384 rows + 8 experts * up-to-255 pad, rounded to 256

typedef float          f32x4   __attribute__((ext_vector_type(4)));
typedef short          bf16x8  __attribute__((ext_vector_type(8)));
typedef unsigned short u16x4   __attribute__((ext_vector_type(4)));

static __device__ __forceinline__ unsigned short f2bf(float f) {
  unsigned int u = __builtin_bit_cast(unsigned int, f);
  u = (u + 0x7FFFu + ((u >> 16) & 1u)) >> 16;   // round-nearest-even (finite inputs)
  return (unsigned short)u;
}

// async global->LDS, 16B per lane; LDS dest = wave-uniform base + lane*16
static __device__ __forceinline__ void gl16(const void* g, void* l) {
  __builtin_amdgcn_global_load_lds(
      (const __attribute__((address_space(1))) unsigned int*)g,
      (__attribute__((address_space(3))) unsigned int*)l,
      16, 0, 0);
}

#define FENCE() asm volatile("" ::: "memory")

// ---------------- router: logits, top-2, normalized weights, counts ----------
__global__ __launch_bounds__(256) void router_k(const float* __restrict__ x,
                                                const float* __restrict__ Wr,
                                                const float* __restrict__ br,
                                                int* __restrict__ meta,
                                                int2* __restrict__ top_i,
                                                float2* __restrict__ top_w) {
  int lane = threadIdx.x & 63;
  int wid  = threadIdx.x >> 6;
  int t = blockIdx.x * 4 + wid;                  // grid = T/4
  const float* xp = x + (size_t)t * DIM + lane * 16;
  float acc[NEXP];
#pragma unroll
  for (int e = 0; e < NEXP; ++e) acc[e] = 0.f;
#pragma unroll
  for (int j = 0; j < 16; j += 4) {
    float4 xv = *(const float4*)(xp + j);
    const float* wp = Wr + (size_t)(lane * 16 + j) * NEXP;
#pragma unroll
    for (int jj = 0; jj < 4; ++jj) {
      float xs = jj == 0 ? xv.x : jj == 1 ? xv.y : jj == 2 ? xv.z : xv.w;
      float4 w0 = *(const float4*)(wp + jj * NEXP);
      float4 w1 = *(const float4*)(wp + jj * NEXP + 4);
      acc[0] += xs * w0.x; acc[1] += xs * w0.y; acc[2] += xs * w0.z; acc[3] += xs * w0.w;
      acc[4] += xs * w1.x; acc[5] += xs * w1.y; acc[6] += xs * w1.z; acc[7] += xs * w1.w;
    }
  }
#pragma unroll
  for (int off = 32; off > 0; off >>= 1) {
#pragma unroll
    for (int e = 0; e < NEXP; ++e) acc[e] += __shfl_xor(acc[e], off);
  }
  if (lane == 0) {
    float l[NEXP];
#pragma unroll
    for (int e = 0; e < NEXP; ++e) l[e] = acc[e] + br[e];
    int e1 = 0;
#pragma unroll
    for (int e = 1; e < NEXP; ++e) if (l[e] > l[e1]) e1 = e;      // ties -> lower idx
    int e2 = (e1 == 0) ? 1 : 0;
#pragma unroll
    for (int e = 0; e < NEXP; ++e) if (e != e1 && l[e] > l[e2]) e2 = e;
    float g  = expf(l[e2] - l[e1]);              // softmax over top-2 == renorm of full softmax
    float w1 = 1.f / (1.f + g);
    top_i[t] = make_int2(e1, e2);
    top_w[t] = make_float2(w1, 1.f - w1);
    atomicAdd(&meta[e1], 1);
    atomicAdd(&meta[e2], 1);
  }
}

// -------- prefix: padded (x256) offsets ------------------------------------
__global__ void prefix_k(int* __restrict__ meta) {
  if (threadIdx.x == 0) {
    int s = 0;
#pragma unroll
    for (int e = 0; e < NEXP; ++e) {
      meta[16 + e] = s;                          // poff[e]
      s += (meta[e] + 255) & ~255;
    }
    meta[24] = s;                                // poff[8]
    meta[25] = s;                                // total_padded (<= MAXR always)
  }
}

// -------- fill: default row arrays (pad rows: token 0, weight 0) -------------
__global__ __launch_bounds__(256) void fill_k(int* __restrict__ tok_of_row,
                                              float* __restrict__ wt_of_row) {
  int i = blockIdx.x * 256 + threadIdx.x;
  if (i < MAXR) { tok_of_row[i] = 0; wt_of_row[i] = 0.f; }
}

// ---------------- scatter: token -> packed expert row ------------------------
__global__ __launch_bounds__(256) void scatter_k(const int2* __restrict__ top_i,
                                                 const float2* __restrict__ top_w,
                                                 int* __restrict__ meta,
                                                 int* __restrict__ row_of,
                                                 int* __restrict__ tok_of_row,
                                                 float* __restrict__ wt_of_row) {
  int t = blockIdx.x * 256 + threadIdx.x;
  int2  ei = top_i[t];
  float2 w = top_w[t];
  int p = atomicAdd(&meta[8 + ei.x], 1);
  int r = meta[16 + ei.x] + p;
  tok_of_row[r] = t; wt_of_row[r] = w.x; row_of[t * 2] = r;
  p = atomicAdd(&meta[8 + ei.y], 1);
  r = meta[16 + ei.y] + p;
  tok_of_row[r] = t; wt_of_row[r] = w.y; row_of[t * 2 + 1] = r;
}

// ---------------- gather: xg[r][:] = bf16(x[tok[r]][:]) ----------------------
__global__ __launch_bounds__(256) void gather_k(const float* __restrict__ x,
                                                const int* __restrict__ tok_of_row,
                                                const int* __restrict__ meta,
                                                unsigned short* __restrict__ xg) {
  int r = blockIdx.x;
  if (r >= meta[25]) return;
  int t = tok_of_row[r];
  int c = threadIdx.x * 4;
  float4 v = *(const float4*)(x + (size_t)t * DIM + c);
  u16x4 o;
  o[0] = f2bf(v.x); o[1] = f2bf(v.y); o[2] = f2bf(v.z); o[3] = f2bf(v.w);
  *(u16x4*)(xg + (size_t)r * DIM + c) = o;
}

// -------- transpose + fp32->bf16: W[e][R][C] -> WT[e][C][R] ------------------
__global__ __launch_bounds__(256) void transpose_convert_k(const float* __restrict__ W,
                                                           unsigned short* __restrict__ WT,
                                                           int R, int C) {
  __shared__ float tile[32][33];
  int e = blockIdx.z;
  int c0 = blockIdx.x * 32, r0 = blockIdx.y * 32;
  const float* Wp = W + (size_t)e * R * C;
  unsigned short* Op = WT + (size_t)e * R * C;
  int tr = threadIdx.x >> 3;
  int tc = (threadIdx.x & 7) * 4;
  float4 v = *(const float4*)(Wp + (size_t)(r0 + tr) * C + c0 + tc);
  tile[tr][tc] = v.x; tile[tr][tc + 1] = v.y; tile[tr][tc + 2] = v.z; tile[tr][tc + 3] = v.w;
  __syncthreads();
  int oc  = threadIdx.x >> 3;
  int orr = (threadIdx.x & 7) * 4;
  u16x4 o;
#pragma unroll
  for (int j = 0; j < 4; ++j) o[j] = f2bf(tile[orr + j][oc]);
  *(u16x4*)(Op + (size_t)(c0 + oc) * R + r0 + orr) = o;
}

// ---------------- 8-phase 256x256 grouped GEMM -------------------------------
// A: [M][KTOT] bf16 packed rows.  Bt: [E][NTOT][KTOT] bf16 (pre-transposed).
// 512 thr (8 waves 2Mx4N), BK=64, 128KiB LDS double-buffered, K-half half-tiles,
// counted vmcnt(6), T2 slot-XOR swizzle, T5 setprio around MFMA clusters.
// Phase(kh, mh): 8x ds_read_b128, 16x mfma_16x16x32_bf16 on quadrant (mh, kh).
// EPI 0: h = bf16(gelu(acc + b1[e][n]))  EPI 1: atomicAdd out[tok[m]] += (acc+b2[n])*wt[m]

template <int KH, int MH>
__device__ __forceinline__ void do_phase(const unsigned short* lds_, int buf,
                                         int aoff, int boff, f32x4 (&acc)[8][4]) {
  const unsigned short* Ar = lds_ + (buf * 4 + KH) * 8192 + aoff + MH * 2048;
  const unsigned short* Br = lds_ + (buf * 4 + 2 + KH) * 8192 + boff;
  bf16x8 af[4], bv[4];
#pragma unroll
  for (int r = 0; r < 4; ++r) af[r] = *(const bf16x8*)(Ar + r * 512);
#pragma unroll
  for (int n = 0; n < 4; ++n) bv[n] = *(const bf16x8*)(Br + n * 512);
  __builtin_amdgcn_s_setprio(1);
#pragma unroll
  for (int r = 0; r < 4; ++r)
#pragma unroll
    for (int n = 0; n < 4; ++n)
      acc[MH * 4 + r][n] =
          __builtin_amdgcn_mfma_f32_16x16x32_bf16(af[r], bv[n], acc[MH * 4 + r][n], 0, 0, 0);
  __builtin_amdgcn_s_setprio(0);
}

template <int KTOT, int NTOT, int EPI>
__global__ __launch_bounds__(512, 2) void gemm8_k(const unsigned short* __restrict__ A,
                                                  const unsigned short* __restrict__ Bt,
                                                  const float* __restrict__ bias,
                                                  const int* __restrict__ meta,
                                                  const float* __restrict__ wt_of_row,
                                                  const int* __restrict__ tok_of_row,
                                                  void* __restrict__ Cout) {
  constexpr int NTILES = NTOT / 256;
  constexpr int NWG = (MAXR / 256) * NTILES;     // 1152 or 288, both % 8 == 0
  constexpr int NT = KTOT / 64;
  __shared__ __align__(16) unsigned short lds[65536];   // 128 KiB

  int id = ((int)blockIdx.x & 7) * (NWG / 8) + ((int)blockIdx.x >> 3);  // XCD swizzle
  int row0 = (id / NTILES) * 256;                // n-fast within XCD chunk (A-panel reuse)
  int n0   = (id % NTILES) * 256;
  if (row0 >= meta[25]) return;                  // beyond padded total (uniform exit)
  int e = 0;
  while (meta[17 + e] <= row0) ++e;              // tiles never straddle experts
  const unsigned short* Bp = Bt + (size_t)e * NTOT * KTOT;

  int tid = threadIdx.x;
  int lane = tid & 63, wid = tid >> 6;
  int wm = wid >> 2, wn = wid & 3;               // 2x4 waves, each owns 128x64 of C

  // ---- staging precompute: thread covers granules l = i*512 + tid (i=0,1)
  // granule l -> (row = l>>2, slot' = l&3); source slot = slot' ^ ((row>>1)&3)
  int r0s = tid >> 2, r1s = 128 + (tid >> 2);
  int s0 = (tid & 3) ^ ((r0s >> 1) & 3);
  int s1 = (tid & 3) ^ ((r1s >> 1) & 3);
  const unsigned short* pA0 = A + (size_t)(row0 + r0s) * KTOT + s0 * 8;
  const unsigned short* pA1 = A + (size_t)(row0 + r1s) * KTOT + s1 * 8;
  const unsigned short* pB0 = Bp + (size_t)(n0 + r0s) * KTOT + s0 * 8;
  const unsigned short* pB1 = Bp + (size_t)(n0 + r1s) * KTOT + s1 * 8;
  int ldst = wid * 512;                          // wave-uniform LDS granule base

  auto stage = [&](int bufx, int mat, int kh, int kt) {
    int rb = (bufx * 4 + mat * 2 + kh) * 8192 + ldst;
    int ko = kt * 64 + kh * 32;
    gl16((mat ? pB0 : pA0) + ko, (void*)(lds + rb));
    gl16((mat ? pB1 : pA1) + ko, (void*)(lds + rb + 4096));
  };

  // ---- fragment read bases (swizzled): slot' = g ^ ((lane>>1)&3), g = lane>>4
  int sF = ((lane >> 4) ^ ((lane >> 1) & 3)) * 8;
  int aoff = wm * 4096 + (lane & 15) * 32 + sF;
  int boff = wn * 2048 + (lane & 15) * 32 + sF;

  f32x4 acc[8][4];
#pragma unroll
  for (int r = 0; r < 8; ++r)
#pragma unroll
    for (int n = 0; n < 4; ++n) acc[r][n] = (f32x4){0.f, 0.f, 0.f, 0.f};

  // ---- prologue: stage tile 0 (order B-k0, A-k0, B-k1, A-k1) into buf 0
  stage(0, 1, 0, 0); stage(0, 0, 0, 0); stage(0, 1, 1, 0); stage(0, 0, 1, 0);
  FENCE();

  // ---- steady loop: compute tile t from buf, stage tile t+1 into buf^1
  for (int t = 0; t < NT - 1; ++t) {
    int buf = t & 1, nb = buf ^ 1;
    stage(nb, 1, 0, t + 1);
    asm volatile("s_waitcnt vmcnt(6)" ::: "memory");
    __builtin_amdgcn_s_barrier(); FENCE();
    do_phase<0, 0>(lds, buf, aoff, boff, acc);
    stage(nb, 0, 0, t + 1); FENCE();
    __builtin_amdgcn_s_barrier(); FENCE();
    do_phase<0, 1>(lds, buf, aoff, boff, acc);
    stage(nb, 1, 1, t + 1);
    asm volatile("s_waitcnt vmcnt(6)" ::: "memory");
    __builtin_amdgcn_s_barrier(); FENCE();
    do_phase<1, 0>(lds, buf, aoff, boff, acc);
    stage(nb, 0, 1, t + 1); FENCE();
    __builtin_amdgcn_s_barrier(); FENCE();
    do_phase<1, 1>(lds, buf, aoff, boff, acc);
  }
  // ---- last tile: no staging; drain progressively
  {
    int buf = (NT - 1) & 1;
    asm volatile("s_waitcnt vmcnt(4)" ::: "memory");
    __builtin_amdgcn_s_barrier(); FENCE();
    do_phase<0, 0>(lds, buf, aoff, boff, acc);
    __builtin_amdgcn_s_barrier(); FENCE();
    do_phase<0, 1>(lds, buf, aoff, boff, acc);
    asm volatile("s_waitcnt vmcnt(0)" ::: "memory");
    __builtin_amdgcn_s_barrier(); FENCE();
    do_phase<1, 0>(lds, buf, aoff, boff, acc);
    __builtin_amdgcn_s_barrier(); FENCE();
    do_phase<1, 1>(lds, buf, aoff, boff, acc);
  }

  // ---- epilogue.  C/D: col = lane&15, row = (lane>>4)*4 + reg
  int rb2 = row0 + wm * 128 + ((lane >> 4) << 2);
  int nb2 = n0 + wn * 64 + (lane & 15);
  if constexpr (EPI == 0) {
    unsigned short* Hp = (unsigned short*)Cout;
    const float* bp = bias + (size_t)e * NTOT;
#pragma unroll
    for (int r = 0; r < 8; ++r)
#pragma unroll
      for (int n = 0; n < 4; ++n) {
        int ncol = nb2 + n * 16;
        float bv = bp[ncol];
#pragma unroll
        for (int g = 0; g < 4; ++g) {
          int m = rb2 + r * 16 + g;
          float v = acc[r][n][g] + bv;
          v = 0.5f * v * (1.f + erff(v * 0.70710678118654752f));   // exact gelu
          Hp[(size_t)m * NTOT + ncol] = f2bf(v);
        }
      }
  } else {
    float* Op = (float*)Cout;
    const float* bp = bias + (size_t)e * NTOT;
#pragma unroll
    for (int r = 0; r < 8; ++r)
#pragma unroll
      for (int g = 0; g < 4; ++g) {
        int m = rb2 + r * 16 + g;
        float wt = wt_of_row[m];
        if (wt != 0.f) {                         // pad rows excluded (wt exactly 0)
          float* orow = Op + (size_t)tok_of_row[m] * DIM;
#pragma unroll
          for (int n = 0; n < 4; ++n) {
            int ncol = nb2 + n * 16;
            atomicAdd(orow + ncol, (acc[r][n][g] + bp[ncol]) * wt);
          }
        }
      }
  }
}

extern "C" void kernel_launch(void* const* d_in, const int* in_sizes, int n_in,
                              void* d_out, int out_size, void* d_ws, size_t ws_size,
                              hipStream_t stream) {
  const float* x  = (const float*)d_in[0];
  const float* Wr = (const float*)d_in[1];
  const float* br = (const float*)d_in[2];
  const float* W1 = (const float*)d_in[3];
  const float* b1 = (const float*)d_in[4];
  const float* W2 = (const float*)d_in[5];
  const float* b2 = (const float*)d_in[6];
  float* out = (float*)d_out;

  char* base = (char*)d_ws;
  size_t off = 0;
  auto carve = [&](size_t bytes) -> void* {
    void* r = base + off;
    off = (off + bytes + 255) & ~(size_t)255;
    return r;
  };
  int*            meta       = (int*)carve(26 * 4);
  int2*           top_i      = (int2*)carve((size_t)T_TOK * 8);
  float2*         top_w      = (float2*)carve((size_t)T_TOK * 8);
  int*            row_of     = (int*)carve((size_t)T_TOK * 2 * 4);
  int*            tok_of_row = (int*)carve((size_t)MAXR * 4);
  float*          wt_of_row  = (float*)carve((size_t)MAXR * 4);
  unsigned short* xg         = (unsigned short*)carve((size_t)MAXR * DIM * 2);
  unsigned short* W1bT       = (unsigned short*)carve((size_t)NEXP * DIM * HID * 2);
  unsigned short* W2bT       = (unsigned short*)carve((size_t)NEXP * DIM * HID * 2);
  unsigned short* hbuf       = (unsigned short*)carve((size_t)MAXR * HID * 2);
  if (off > ws_size) {
    fprintf(stderr, "kernel_launch: ws_size too small: need %zu have %zu\n", off, ws_size);
    return;
  }

  hipMemsetAsync(meta, 0, 26 * 4, stream);
  hipMemsetAsync(out, 0, (size_t)out_size * 4, stream);   // GEMM2 atomicAdds into out
  hipLaunchKernelGGL(transpose_convert_k, dim3(HID / 32, DIM / 32, NEXP), dim3(256), 0, stream,
                     W1, W1bT, DIM, HID);                 // W1[e][D][H] -> [e][H][D]
  hipLaunchKernelGGL(transpose_convert_k, dim3(DIM / 32, HID / 32, NEXP), dim3(256), 0, stream,
                     W2, W2bT, HID, DIM);                 // W2[e][H][D] -> [e][D][H]
  hipLaunchKernelGGL(fill_k, dim3((MAXR + 255) / 256), dim3(256), 0, stream,
                     tok_of_row, wt_of_row);
  hipLaunchKernelGGL(router_k, dim3(T_TOK / 4), dim3(256), 0, stream,
                     x, Wr, br, meta, top_i, top_w);
  hipLaunchKernelGGL(prefix_k, dim3(1), dim3(64), 0, stream, meta);
  hipLaunchKernelGGL(scatter_k, dim3(T_TOK / 256), dim3(256), 0, stream,
                     top_i, top_w, meta, row_of, tok_of_row, wt_of_row);
  hipLaunchKernelGGL(gather_k, dim3(MAXR), dim3(256), 0, stream, x, tok_of_row, meta, xg);
  hipLaunchKernelGGL((gemm8_k<DIM, HID, 0>), dim3((MAXR / 256) * (HID / 256)), dim3(512), 0,
                     stream, xg, W1bT, b1, meta, wt_of_row, tok_of_row, (void*)hbuf);
  hipLaunchKernelGGL((gemm8_k<HID, DIM, 1>), dim3((MAXR / 256) * (DIM / 256)), dim3(512), 0,
                     stream, hbuf, W2bT, b2, meta, wt_of_row, tok_of_row, (void*)out);
}

// Round 4
// 949.434 us; speedup vs baseline: 1.0033x; 1.0033x over previous
//
#include <hip/hip_runtime.h>
#include <cstdio>

// MoE top-2 FFN: B=4,S=2048,D=1024 -> T=8192 tokens; E=8, H=4096, K_TOP=2.
// Round 4: 8-phase GEMM with COMPILE-TIME double-buffer regions (x2 unrolled
// K-loop), m201-faithful phase order {ds_read; stage; bar; lgkm0; mfma; bar},
// counted vmcnt(4) at phases 1/3 end-barriers. Non-GEMM parts unchanged.

#define T_TOK 8192
#define DIM   1024
#define NEXP  8
#define HID   4096
#define MAXR  18432  // 16384 rows + 8 experts * up-to-255 pad, rounded to 256

typedef float          f32x4   __attribute__((ext_vector_type(4)));
typedef short          bf16x8  __attribute__((ext_vector_type(8)));
typedef unsigned short u16x4   __attribute__((ext_vector_type(4)));

static __device__ __forceinline__ unsigned short f2bf(float f) {
  unsigned int u = __builtin_bit_cast(unsigned int, f);
  u = (u + 0x7FFFu + ((u >> 16) & 1u)) >> 16;   // round-nearest-even (finite inputs)
  return (unsigned short)u;
}

// async global->LDS, 16B per lane; LDS dest = wave-uniform base + lane*16
static __device__ __forceinline__ void gl16(const void* g, void* l) {
  __builtin_amdgcn_global_load_lds(
      (const __attribute__((address_space(1))) unsigned int*)g,
      (__attribute__((address_space(3))) unsigned int*)l,
      16, 0, 0);
}

#define FENCE() asm volatile("" ::: "memory")
#define BAR()   do { FENCE(); __builtin_amdgcn_s_barrier(); FENCE(); } while (0)
#define LGKM0() asm volatile("s_waitcnt lgkmcnt(0)" ::: "memory")
#define VMW4()  asm volatile("s_waitcnt vmcnt(4)" ::: "memory")
#define VMW0()  asm volatile("s_waitcnt vmcnt(0)" ::: "memory")

// ---------------- router: logits, top-2, normalized weights, counts ----------
__global__ __launch_bounds__(256) void router_k(const float* __restrict__ x,
                                                const float* __restrict__ Wr,
                                                const float* __restrict__ br,
                                                int* __restrict__ meta,
                                                int2* __restrict__ top_i,
                                                float2* __restrict__ top_w) {
  int lane = threadIdx.x & 63;
  int wid  = threadIdx.x >> 6;
  int t = blockIdx.x * 4 + wid;                  // grid = T/4
  const float* xp = x + (size_t)t * DIM + lane * 16;
  float acc[NEXP];
#pragma unroll
  for (int e = 0; e < NEXP; ++e) acc[e] = 0.f;
#pragma unroll
  for (int j = 0; j < 16; j += 4) {
    float4 xv = *(const float4*)(xp + j);
    const float* wp = Wr + (size_t)(lane * 16 + j) * NEXP;
#pragma unroll
    for (int jj = 0; jj < 4; ++jj) {
      float xs = jj == 0 ? xv.x : jj == 1 ? xv.y : jj == 2 ? xv.z : xv.w;
      float4 w0 = *(const float4*)(wp + jj * NEXP);
      float4 w1 = *(const float4*)(wp + jj * NEXP + 4);
      acc[0] += xs * w0.x; acc[1] += xs * w0.y; acc[2] += xs * w0.z; acc[3] += xs * w0.w;
      acc[4] += xs * w1.x; acc[5] += xs * w1.y; acc[6] += xs * w1.z; acc[7] += xs * w1.w;
    }
  }
#pragma unroll
  for (int off = 32; off > 0; off >>= 1) {
#pragma unroll
    for (int e = 0; e < NEXP; ++e) acc[e] += __shfl_xor(acc[e], off);
  }
  if (lane == 0) {
    float l[NEXP];
#pragma unroll
    for (int e = 0; e < NEXP; ++e) l[e] = acc[e] + br[e];
    int e1 = 0;
#pragma unroll
    for (int e = 1; e < NEXP; ++e) if (l[e] > l[e1]) e1 = e;      // ties -> lower idx
    int e2 = (e1 == 0) ? 1 : 0;
#pragma unroll
    for (int e = 0; e < NEXP; ++e) if (e != e1 && l[e] > l[e2]) e2 = e;
    float g  = expf(l[e2] - l[e1]);              // softmax over top-2 == renorm of full softmax
    float w1 = 1.f / (1.f + g);
    top_i[t] = make_int2(e1, e2);
    top_w[t] = make_float2(w1, 1.f - w1);
    atomicAdd(&meta[e1], 1);
    atomicAdd(&meta[e2], 1);
  }
}

// -------- prefix: padded (x256) offsets ------------------------------------
__global__ void prefix_k(int* __restrict__ meta) {
  if (threadIdx.x == 0) {
    int s = 0;
#pragma unroll
    for (int e = 0; e < NEXP; ++e) {
      meta[16 + e] = s;                          // poff[e]
      s += (meta[e] + 255) & ~255;
    }
    meta[24] = s;                                // poff[8]
    meta[25] = s;                                // total_padded (<= MAXR always)
  }
}

// -------- fill: default row arrays (pad rows: token 0, weight 0) -------------
__global__ __launch_bounds__(256) void fill_k(int* __restrict__ tok_of_row,
                                              float* __restrict__ wt_of_row) {
  int i = blockIdx.x * 256 + threadIdx.x;
  if (i < MAXR) { tok_of_row[i] = 0; wt_of_row[i] = 0.f; }
}

// ---------------- scatter: token -> packed expert row ------------------------
__global__ __launch_bounds__(256) void scatter_k(const int2* __restrict__ top_i,
                                                 const float2* __restrict__ top_w,
                                                 int* __restrict__ meta,
                                                 int* __restrict__ row_of,
                                                 int* __restrict__ tok_of_row,
                                                 float* __restrict__ wt_of_row) {
  int t = blockIdx.x * 256 + threadIdx.x;
  int2  ei = top_i[t];
  float2 w = top_w[t];
  int p = atomicAdd(&meta[8 + ei.x], 1);
  int r = meta[16 + ei.x] + p;
  tok_of_row[r] = t; wt_of_row[r] = w.x; row_of[t * 2] = r;
  p = atomicAdd(&meta[8 + ei.y], 1);
  r = meta[16 + ei.y] + p;
  tok_of_row[r] = t; wt_of_row[r] = w.y; row_of[t * 2 + 1] = r;
}

// ---------------- gather: xg[r][:] = bf16(x[tok[r]][:]) ----------------------
__global__ __launch_bounds__(256) void gather_k(const float* __restrict__ x,
                                                const int* __restrict__ tok_of_row,
                                                const int* __restrict__ meta,
                                                unsigned short* __restrict__ xg) {
  int r = blockIdx.x;
  if (r >= meta[25]) return;
  int t = tok_of_row[r];
  int c = threadIdx.x * 4;
  float4 v = *(const float4*)(x + (size_t)t * DIM + c);
  u16x4 o;
  o[0] = f2bf(v.x); o[1] = f2bf(v.y); o[2] = f2bf(v.z); o[3] = f2bf(v.w);
  *(u16x4*)(xg + (size_t)r * DIM + c) = o;
}

// -------- transpose + fp32->bf16: W[e][R][C] -> WT[e][C][R] ------------------
__global__ __launch_bounds__(256) void transpose_convert_k(const float* __restrict__ W,
                                                           unsigned short* __restrict__ WT,
                                                           int R, int C) {
  __shared__ float tile[32][33];
  int e = blockIdx.z;
  int c0 = blockIdx.x * 32, r0 = blockIdx.y * 32;
  const float* Wp = W + (size_t)e * R * C;
  unsigned short* Op = WT + (size_t)e * R * C;
  int tr = threadIdx.x >> 3;
  int tc = (threadIdx.x & 7) * 4;
  float4 v = *(const float4*)(Wp + (size_t)(r0 + tr) * C + c0 + tc);
  tile[tr][tc] = v.x; tile[tr][tc + 1] = v.y; tile[tr][tc + 2] = v.z; tile[tr][tc + 3] = v.w;
  __syncthreads();
  int oc  = threadIdx.x >> 3;
  int orr = (threadIdx.x & 7) * 4;
  u16x4 o;
#pragma unroll
  for (int j = 0; j < 4; ++j) o[j] = f2bf(tile[orr + j][oc]);
  *(u16x4*)(Op + (size_t)(c0 + oc) * R + r0 + orr) = o;
}

// ---------------- 8-phase 256x256 grouped GEMM -------------------------------
// LDS regions (16KB = 8192 shorts each): (BUF*4 + mat*2 + kh), mat A=0 B=1.
// Region layout: [256 rows][4 slots of 8 shorts], slot XOR-swizzled by (row>>1)&3.
// Per K-tile: 4 phases (kh,mh) = (0,0),(0,1),(1,0),(1,1); each phase:
//   ds_read frags -> stage one half-tile of next K-tile -> BAR -> lgkm0 ->
//   setprio(1) 16x MFMA setprio(0) -> [vmcnt(4) @PH1,PH3] -> BAR.

template <int RB>
__device__ __forceinline__ void mfma16(const bf16x8 (&af)[4], const bf16x8 (&bv)[4],
                                       f32x4 (&acc)[8][4]) {
  __builtin_amdgcn_s_setprio(1);
#pragma unroll
  for (int r = 0; r < 4; ++r)
#pragma unroll
    for (int n = 0; n < 4; ++n)
      acc[RB + r][n] =
          __builtin_amdgcn_mfma_f32_16x16x32_bf16(af[r], bv[n], acc[RB + r][n], 0, 0, 0);
  __builtin_amdgcn_s_setprio(0);
}

template <int BUF, bool STAGE, bool LAST>
__device__ __forceinline__ void tile_k(unsigned short* lds, int ko,
                                       const unsigned short* pA0, const unsigned short* pA1,
                                       const unsigned short* pB0, const unsigned short* pB1,
                                       int ldst, int aoff, int boff, f32x4 (&acc)[8][4]) {
  constexpr int NB = BUF ^ 1;
  bf16x8 af[4], bv[4];

  // stage one half-tile (mat, kh) of the next K-tile into buf NB (compile-time region)
  auto stg = [&](int mat, int kh) {
    if constexpr (STAGE) {
      int rb = (NB * 4 + mat * 2 + kh) * 8192 + ldst;     // NB,mat,kh compile-time-foldable
      const unsigned short* s0 = (mat ? pB0 : pA0) + ko + kh * 32;
      const unsigned short* s1 = (mat ? pB1 : pA1) + ko + kh * 32;
      gl16(s0, (void*)(lds + rb));
      gl16(s1, (void*)(lds + rb + 4096));
    }
  };

  // ---- PH0: (k0, mh0) --------------------------------------------------
#pragma unroll
  for (int n = 0; n < 4; ++n) bv[n] = *(const bf16x8*)(lds + (BUF * 4 + 2) * 8192 + boff + n * 512);
#pragma unroll
  for (int r = 0; r < 4; ++r) af[r] = *(const bf16x8*)(lds + (BUF * 4 + 0) * 8192 + aoff + r * 512);
  stg(1, 0);
  BAR(); LGKM0();
  mfma16<0>(af, bv, acc);
  BAR();
  // ---- PH1: (k0, mh1) — reuse bv ---------------------------------------
#pragma unroll
  for (int r = 0; r < 4; ++r)
    af[r] = *(const bf16x8*)(lds + (BUF * 4 + 0) * 8192 + aoff + 2048 + r * 512);
  stg(0, 0);
  BAR(); LGKM0();
  mfma16<4>(af, bv, acc);
  if constexpr (STAGE) { VMW4(); } else if constexpr (LAST) { VMW0(); }
  BAR();
  // ---- PH2: (k1, mh0) --------------------------------------------------
#pragma unroll
  for (int n = 0; n < 4; ++n) bv[n] = *(const bf16x8*)(lds + (BUF * 4 + 3) * 8192 + boff + n * 512);
#pragma unroll
  for (int r = 0; r < 4; ++r) af[r] = *(const bf16x8*)(lds + (BUF * 4 + 1) * 8192 + aoff + r * 512);
  stg(1, 1);
  BAR(); LGKM0();
  mfma16<0>(af, bv, acc);
  BAR();
  // ---- PH3: (k1, mh1) — reuse bv ---------------------------------------
#pragma unroll
  for (int r = 0; r < 4; ++r)
    af[r] = *(const bf16x8*)(lds + (BUF * 4 + 1) * 8192 + aoff + 2048 + r * 512);
  stg(0, 1);
  BAR(); LGKM0();
  mfma16<4>(af, bv, acc);
  if constexpr (STAGE) VMW4();
  BAR();
}

template <int KTOT, int NTOT, int EPI>
__global__ __launch_bounds__(512, 2) void gemm8_k(const unsigned short* __restrict__ A,
                                                  const unsigned short* __restrict__ Bt,
                                                  const float* __restrict__ bias,
                                                  const int* __restrict__ meta,
                                                  const float* __restrict__ wt_of_row,
                                                  const int* __restrict__ tok_of_row,
                                                  void* __restrict__ Cout) {
  constexpr int NTILES = NTOT / 256;
  constexpr int NWG = (MAXR / 256) * NTILES;     // 1152 or 288, both % 8 == 0
  constexpr int NT = KTOT / 64;                  // 16 or 64 (even)
  __shared__ __align__(16) unsigned short lds[65536];   // 128 KiB

  int id = ((int)blockIdx.x & 7) * (NWG / 8) + ((int)blockIdx.x >> 3);  // XCD swizzle
  int row0 = (id / NTILES) * 256;                // n-fast within XCD chunk (A-panel reuse)
  int n0   = (id % NTILES) * 256;
  if (row0 >= meta[25]) return;                  // beyond padded total (uniform exit)
  int e = 0;
  while (meta[17 + e] <= row0) ++e;              // tiles never straddle experts
  const unsigned short* Bp = Bt + (size_t)e * NTOT * KTOT;

  int tid = threadIdx.x;
  int lane = tid & 63, wid = tid >> 6;
  int wm = wid >> 2, wn = wid & 3;               // 2x4 waves, each owns 128x64 of C

  // ---- staging source: granule l = i*512 + tid -> (row = l>>2, slot' = l&3);
  // source slot = slot' ^ ((row>>1)&3)  (T2 swizzle, write side)
  int r0s = tid >> 2, r1s = 128 + (tid >> 2);
  int s0 = (tid & 3) ^ ((r0s >> 1) & 3);
  int s1 = (tid & 3) ^ ((r1s >> 1) & 3);
  const unsigned short* pA0 = A + (size_t)(row0 + r0s) * KTOT + s0 * 8;
  const unsigned short* pA1 = A + (size_t)(row0 + r1s) * KTOT + s1 * 8;
  const unsigned short* pB0 = Bp + (size_t)(n0 + r0s) * KTOT + s0 * 8;
  const unsigned short* pB1 = Bp + (size_t)(n0 + r1s) * KTOT + s1 * 8;
  int ldst = wid * 512;                          // wave-uniform LDS granule base (shorts)

  // ---- fragment read offsets (swizzle read side): slot' = (lane>>4) ^ ((lane>>1)&3)
  int sF = ((lane >> 4) ^ ((lane >> 1) & 3)) * 8;
  int aoff = wm * 4096 + (lane & 15) * 32 + sF;  // + mh*2048 + r*512 in phase
  int boff = wn * 2048 + (lane & 15) * 32 + sF;  // + n*512 in phase

  f32x4 acc[8][4];
#pragma unroll
  for (int r = 0; r < 8; ++r)
#pragma unroll
    for (int n = 0; n < 4; ++n) acc[r][n] = (f32x4){0.f, 0.f, 0.f, 0.f};

  // ---- prologue: stage tile 0 into buf 0, order B-k0, A-k0, B-k1, A-k1
  gl16(pB0, (void*)(lds + 2 * 8192 + ldst)); gl16(pB1, (void*)(lds + 2 * 8192 + ldst + 4096));
  gl16(pA0, (void*)(lds + 0 * 8192 + ldst)); gl16(pA1, (void*)(lds + 0 * 8192 + ldst + 4096));
  gl16(pB0 + 32, (void*)(lds + 3 * 8192 + ldst)); gl16(pB1 + 32, (void*)(lds + 3 * 8192 + ldst + 4096));
  gl16(pA0 + 32, (void*)(lds + 1 * 8192 + ldst)); gl16(pA1 + 32, (void*)(lds + 1 * 8192 + ldst + 4096));
  VMW4(); BAR();

  // ---- main loop: x2 unrolled so buffer regions are compile-time
  for (int t = 0; t < NT - 2; t += 2) {
    tile_k<0, true, false>(lds, (t + 1) * 64, pA0, pA1, pB0, pB1, ldst, aoff, boff, acc);
    tile_k<1, true, false>(lds, (t + 2) * 64, pA0, pA1, pB0, pB1, ldst, aoff, boff, acc);
  }
  tile_k<0, true, false>(lds, (NT - 1) * 64, pA0, pA1, pB0, pB1, ldst, aoff, boff, acc);
  tile_k<1, false, true>(lds, 0, pA0, pA1, pB0, pB1, ldst, aoff, boff, acc);

  // ---- epilogue.  C/D: col = lane&15, row = (lane>>4)*4 + reg
  int rb2 = row0 + wm * 128 + ((lane >> 4) << 2);
  int nb2 = n0 + wn * 64 + (lane & 15);
  if constexpr (EPI == 0) {
    unsigned short* Hp = (unsigned short*)Cout;
    const float* bp = bias + (size_t)e * NTOT;
#pragma unroll
    for (int r = 0; r < 8; ++r)
#pragma unroll
      for (int n = 0; n < 4; ++n) {
        int ncol = nb2 + n * 16;
        float bv = bp[ncol];
#pragma unroll
        for (int g = 0; g < 4; ++g) {
          int m = rb2 + r * 16 + g;
          float v = acc[r][n][g] + bv;
          v = 0.5f * v * (1.f + erff(v * 0.70710678118654752f));   // exact gelu
          Hp[(size_t)m * NTOT + ncol] = f2bf(v);
        }
      }
  } else {
    float* Op = (float*)Cout;
    const float* bp = bias + (size_t)e * NTOT;
#pragma unroll
    for (int r = 0; r < 8; ++r)
#pragma unroll
      for (int g = 0; g < 4; ++g) {
        int m = rb2 + r * 16 + g;
        float wt = wt_of_row[m];
        if (wt != 0.f) {                         // pad rows excluded (wt exactly 0)
          float* orow = Op + (size_t)tok_of_row[m] * DIM;
#pragma unroll
          for (int n = 0; n < 4; ++n) {
            int ncol = nb2 + n * 16;
            atomicAdd(orow + ncol, (acc[r][n][g] + bp[ncol]) * wt);
          }
        }
      }
  }
}

extern "C" void kernel_launch(void* const* d_in, const int* in_sizes, int n_in,
                              void* d_out, int out_size, void* d_ws, size_t ws_size,
                              hipStream_t stream) {
  const float* x  = (const float*)d_in[0];
  const float* Wr = (const float*)d_in[1];
  const float* br = (const float*)d_in[2];
  const float* W1 = (const float*)d_in[3];
  const float* b1 = (const float*)d_in[4];
  const float* W2 = (const float*)d_in[5];
  const float* b2 = (const float*)d_in[6];
  float* out = (float*)d_out;

  char* base = (char*)d_ws;
  size_t off = 0;
  auto carve = [&](size_t bytes) -> void* {
    void* r = base + off;
    off = (off + bytes + 255) & ~(size_t)255;
    return r;
  };
  int*            meta       = (int*)carve(26 * 4);
  int2*           top_i      = (int2*)carve((size_t)T_TOK * 8);
  float2*         top_w      = (float2*)carve((size_t)T_TOK * 8);
  int*            row_of     = (int*)carve((size_t)T_TOK * 2 * 4);
  int*            tok_of_row = (int*)carve((size_t)MAXR * 4);
  float*          wt_of_row  = (float*)carve((size_t)MAXR * 4);
  unsigned short* xg         = (unsigned short*)carve((size_t)MAXR * DIM * 2);
  unsigned short* W1bT       = (unsigned short*)carve((size_t)NEXP * DIM * HID * 2);
  unsigned short* W2bT       = (unsigned short*)carve((size_t)NEXP * DIM * HID * 2);
  unsigned short* hbuf       = (unsigned short*)carve((size_t)MAXR * HID * 2);
  if (off > ws_size) {
    fprintf(stderr, "kernel_launch: ws_size too small: need %zu have %zu\n", off, ws_size);
    return;
  }

  hipMemsetAsync(meta, 0, 26 * 4, stream);
  hipMemsetAsync(out, 0, (size_t)out_size * 4, stream);   // GEMM2 atomicAdds into out
  hipLaunchKernelGGL(transpose_convert_k, dim3(HID / 32, DIM / 32, NEXP), dim3(256), 0, stream,
                     W1, W1bT, DIM, HID);                 // W1[e][D][H] -> [e][H][D]
  hipLaunchKernelGGL(transpose_convert_k, dim3(DIM / 32, HID / 32, NEXP), dim3(256), 0, stream,
                     W2, W2bT, HID, DIM);                 // W2[e][H][D] -> [e][D][H]
  hipLaunchKernelGGL(fill_k, dim3((MAXR + 255) / 256), dim3(256), 0, stream,
                     tok_of_row, wt_of_row);
  hipLaunchKernelGGL(router_k, dim3(T_TOK / 4), dim3(256), 0, stream,
                     x, Wr, br, meta, top_i, top_w);
  hipLaunchKernelGGL(prefix_k, dim3(1), dim3(64), 0, stream, meta);
  hipLaunchKernelGGL(scatter_k, dim3(T_TOK / 256), dim3(256), 0, stream,
                     top_i, top_w, meta, row_of, tok_of_row, wt_of_row);
  hipLaunchKernelGGL(gather_k, dim3(MAXR), dim3(256), 0, stream, x, tok_of_row, meta, xg);
  hipLaunchKernelGGL((gemm8_k<DIM, HID, 0>), dim3((MAXR / 256) * (HID / 256)), dim3(512), 0,
                     stream, xg, W1bT, b1, meta, wt_of_row, tok_of_row, (void*)hbuf);
  hipLaunchKernelGGL((gemm8_k<HID, DIM, 1>), dim3((MAXR / 256) * (DIM / 256)), dim3(512), 0,
                     stream, hbuf, W2bT, b2, meta, wt_of_row, tok_of_row, (void*)out);
}

// Round 5
// 924.872 us; speedup vs baseline: 1.0299x; 1.0266x over previous
//
#include <hip/hip_runtime.h>
#include <cstdio>

// MoE top-2 FFN: B=4,S=2048,D=1024 -> T=8192 tokens; E=8, H=4096, K_TOP=2.
// Round 5: back to the proven 128x128/BK=32/4-wave GEMM, upgraded to a
// triple-buffered one-barrier-per-tile pipeline with counted vmcnt(4) and the
// (verified conflict-free) T2 slot swizzle. 48KB LDS -> 3 blocks/CU TLP.
// GEMM2 atomicAdds into zeroed out (no ybuf/combine).

#define T_TOK 8192
#define DIM   1024
#define NEXP  8
#define HID   4096
#define MAXR  18432  // 16384 rows + 8 experts * up-to-255 pad, rounded to 256

typedef float          f32x4   __attribute__((ext_vector_type(4)));
typedef short          bf16x8  __attribute__((ext_vector_type(8)));
typedef unsigned short u16x4   __attribute__((ext_vector_type(4)));

static __device__ __forceinline__ unsigned short f2bf(float f) {
  unsigned int u = __builtin_bit_cast(unsigned int, f);
  u = (u + 0x7FFFu + ((u >> 16) & 1u)) >> 16;   // round-nearest-even (finite inputs)
  return (unsigned short)u;
}

// async global->LDS, 16B per lane; LDS dest = wave-uniform base + lane*16
static __device__ __forceinline__ void gl16(const void* g, void* l) {
  __builtin_amdgcn_global_load_lds(
      (const __attribute__((address_space(1))) unsigned int*)g,
      (__attribute__((address_space(3))) unsigned int*)l,
      16, 0, 0);
}

#define FENCE() asm volatile("" ::: "memory")

// ---------------- router: logits, top-2, normalized weights, counts ----------
__global__ __launch_bounds__(256) void router_k(const float* __restrict__ x,
                                                const float* __restrict__ Wr,
                                                const float* __restrict__ br,
                                                int* __restrict__ meta,
                                                int2* __restrict__ top_i,
                                                float2* __restrict__ top_w) {
  int lane = threadIdx.x & 63;
  int wid  = threadIdx.x >> 6;
  int t = blockIdx.x * 4 + wid;                  // grid = T/4
  const float* xp = x + (size_t)t * DIM + lane * 16;
  float acc[NEXP];
#pragma unroll
  for (int e = 0; e < NEXP; ++e) acc[e] = 0.f;
#pragma unroll
  for (int j = 0; j < 16; j += 4) {
    float4 xv = *(const float4*)(xp + j);
    const float* wp = Wr + (size_t)(lane * 16 + j) * NEXP;
#pragma unroll
    for (int jj = 0; jj < 4; ++jj) {
      float xs = jj == 0 ? xv.x : jj == 1 ? xv.y : jj == 2 ? xv.z : xv.w;
      float4 w0 = *(const float4*)(wp + jj * NEXP);
      float4 w1 = *(const float4*)(wp + jj * NEXP + 4);
      acc[0] += xs * w0.x; acc[1] += xs * w0.y; acc[2] += xs * w0.z; acc[3] += xs * w0.w;
      acc[4] += xs * w1.x; acc[5] += xs * w1.y; acc[6] += xs * w1.z; acc[7] += xs * w1.w;
    }
  }
#pragma unroll
  for (int off = 32; off > 0; off >>= 1) {
#pragma unroll
    for (int e = 0; e < NEXP; ++e) acc[e] += __shfl_xor(acc[e], off);
  }
  if (lane == 0) {
    float l[NEXP];
#pragma unroll
    for (int e = 0; e < NEXP; ++e) l[e] = acc[e] + br[e];
    int e1 = 0;
#pragma unroll
    for (int e = 1; e < NEXP; ++e) if (l[e] > l[e1]) e1 = e;      // ties -> lower idx
    int e2 = (e1 == 0) ? 1 : 0;
#pragma unroll
    for (int e = 0; e < NEXP; ++e) if (e != e1 && l[e] > l[e2]) e2 = e;
    float g  = expf(l[e2] - l[e1]);              // softmax over top-2 == renorm of full softmax
    float w1 = 1.f / (1.f + g);
    top_i[t] = make_int2(e1, e2);
    top_w[t] = make_float2(w1, 1.f - w1);
    atomicAdd(&meta[e1], 1);
    atomicAdd(&meta[e2], 1);
  }
}

// -------- prefix: padded (x256) offsets ------------------------------------
__global__ void prefix_k(int* __restrict__ meta) {
  if (threadIdx.x == 0) {
    int s = 0;
#pragma unroll
    for (int e = 0; e < NEXP; ++e) {
      meta[16 + e] = s;                          // poff[e]
      s += (meta[e] + 255) & ~255;
    }
    meta[24] = s;                                // poff[8]
    meta[25] = s;                                // total_padded (<= MAXR always)
  }
}

// -------- fill: default row arrays (pad rows: token 0, weight 0) -------------
__global__ __launch_bounds__(256) void fill_k(int* __restrict__ tok_of_row,
                                              float* __restrict__ wt_of_row) {
  int i = blockIdx.x * 256 + threadIdx.x;
  if (i < MAXR) { tok_of_row[i] = 0; wt_of_row[i] = 0.f; }
}

// ---------------- scatter: token -> packed expert row ------------------------
__global__ __launch_bounds__(256) void scatter_k(const int2* __restrict__ top_i,
                                                 const float2* __restrict__ top_w,
                                                 int* __restrict__ meta,
                                                 int* __restrict__ row_of,
                                                 int* __restrict__ tok_of_row,
                                                 float* __restrict__ wt_of_row) {
  int t = blockIdx.x * 256 + threadIdx.x;
  int2  ei = top_i[t];
  float2 w = top_w[t];
  int p = atomicAdd(&meta[8 + ei.x], 1);
  int r = meta[16 + ei.x] + p;
  tok_of_row[r] = t; wt_of_row[r] = w.x; row_of[t * 2] = r;
  p = atomicAdd(&meta[8 + ei.y], 1);
  r = meta[16 + ei.y] + p;
  tok_of_row[r] = t; wt_of_row[r] = w.y; row_of[t * 2 + 1] = r;
}

// ---------------- gather: xg[r][:] = bf16(x[tok[r]][:]) ----------------------
__global__ __launch_bounds__(256) void gather_k(const float* __restrict__ x,
                                                const int* __restrict__ tok_of_row,
                                                const int* __restrict__ meta,
                                                unsigned short* __restrict__ xg) {
  int r = blockIdx.x;
  if (r >= meta[25]) return;
  int t = tok_of_row[r];
  int c = threadIdx.x * 4;
  float4 v = *(const float4*)(x + (size_t)t * DIM + c);
  u16x4 o;
  o[0] = f2bf(v.x); o[1] = f2bf(v.y); o[2] = f2bf(v.z); o[3] = f2bf(v.w);
  *(u16x4*)(xg + (size_t)r * DIM + c) = o;
}

// -------- transpose + fp32->bf16: W[e][R][C] -> WT[e][C][R] ------------------
__global__ __launch_bounds__(256) void transpose_convert_k(const float* __restrict__ W,
                                                           unsigned short* __restrict__ WT,
                                                           int R, int C) {
  __shared__ float tile[32][33];
  int e = blockIdx.z;
  int c0 = blockIdx.x * 32, r0 = blockIdx.y * 32;
  const float* Wp = W + (size_t)e * R * C;
  unsigned short* Op = WT + (size_t)e * R * C;
  int tr = threadIdx.x >> 3;
  int tc = (threadIdx.x & 7) * 4;
  float4 v = *(const float4*)(Wp + (size_t)(r0 + tr) * C + c0 + tc);
  tile[tr][tc] = v.x; tile[tr][tc + 1] = v.y; tile[tr][tc + 2] = v.z; tile[tr][tc + 3] = v.w;
  __syncthreads();
  int oc  = threadIdx.x >> 3;
  int orr = (threadIdx.x & 7) * 4;
  u16x4 o;
#pragma unroll
  for (int j = 0; j < 4; ++j) o[j] = f2bf(tile[orr + j][oc]);
  *(u16x4*)(Op + (size_t)(c0 + oc) * R + r0 + orr) = o;
}

// ---------------- triple-buffered grouped GEMM (128x128, BK=32) --------------
// LDS: 3 bufs x 16KB; buf c: A at c*8192 shorts, B at c*8192+4096.
// Region = [128 rows][4 slots x 8 shorts], slot XOR-swizzled by (row>>1)&3.
// Per K-tile t: stage buf[(t+1)%3] (4 gl16/wave) -> vmcnt(4) -> s_barrier ->
//               ds_read 8x b128 from buf[t%3] -> 16x mfma_16x16x32_bf16.
// WAR safety: buf[(t+1)%3] was last read at tile t-2; those reads complete
// before that wave's lgkm waits, and barrier t-1 + barrier t order them
// before this stage. RAW safety: vmcnt(4) retires tile t-1's 4 stage loads
// (oldest) which filled buf[t%3]; barrier makes that cross-wave.

template <int CUR, bool STG, bool LAST>
__device__ __forceinline__ void ktile(unsigned short* lds, int ko,
                                      const unsigned short* pA0, const unsigned short* pA1,
                                      const unsigned short* pB0, const unsigned short* pB1,
                                      int stL, int aoff, int boff, f32x4 (&acc)[4][4]) {
  constexpr int NXT = (CUR + 1) % 3;
  if constexpr (STG) {
    gl16(pA0 + ko, lds + NXT * 8192 + stL);
    gl16(pA1 + ko, lds + NXT * 8192 + stL + 2048);
    gl16(pB0 + ko, lds + NXT * 8192 + 4096 + stL);
    gl16(pB1 + ko, lds + NXT * 8192 + 4096 + stL + 2048);
    asm volatile("s_waitcnt vmcnt(4)" ::: "memory");
  } else {
    asm volatile("s_waitcnt vmcnt(0)" ::: "memory");
  }
  __builtin_amdgcn_s_barrier();
  FENCE();
  bf16x8 af[4], bv[4];
#pragma unroll
  for (int i = 0; i < 4; ++i)
    af[i] = *(const bf16x8*)(lds + CUR * 8192 + aoff + i * 512);
#pragma unroll
  for (int j = 0; j < 4; ++j)
    bv[j] = *(const bf16x8*)(lds + CUR * 8192 + boff + j * 512);
  __builtin_amdgcn_s_setprio(1);
#pragma unroll
  for (int i = 0; i < 4; ++i)
#pragma unroll
    for (int j = 0; j < 4; ++j)
      acc[i][j] = __builtin_amdgcn_mfma_f32_16x16x32_bf16(af[i], bv[j], acc[i][j], 0, 0, 0);
  __builtin_amdgcn_s_setprio(0);
  (void)ko;
}

template <int KTOT, int NTOT, int EPI>
__global__ __launch_bounds__(256, 3) void gemm3_k(const unsigned short* __restrict__ A,
                                                  const unsigned short* __restrict__ Bt,
                                                  const float* __restrict__ bias,
                                                  const int* __restrict__ meta,
                                                  const float* __restrict__ wt_of_row,
                                                  const int* __restrict__ tok_of_row,
                                                  void* __restrict__ Cout) {
  constexpr int NXB = MAXR / 128;                // 144 row tiles
  constexpr int NWG = NXB * (NTOT / 128);        // 4608 or 1152, both % 8 == 0
  constexpr int NKT = KTOT / 32;                 // 32 or 128
  static_assert(NKT % 3 == 2, "tail handling assumes NKT % 3 == 2");
  __shared__ __align__(16) unsigned short lds[24576];   // 48 KiB

  int id = ((int)blockIdx.x & 7) * (NWG / 8) + ((int)blockIdx.x >> 3);  // XCD swizzle
  int row0 = (id % NXB) * 128;                   // row-fast within chunk: B-panel L2 reuse
  int n0   = (id / NXB) * 128;
  if (row0 >= meta[25]) return;                  // beyond padded total (block-uniform)
  int e = 0;
  while (meta[17 + e] <= row0) ++e;              // tiles never straddle experts
  const unsigned short* Bp = Bt + (size_t)e * NTOT * KTOT;

  int tid = threadIdx.x;
  int lane = tid & 63, wid = tid >> 6;
  int wm = wid >> 1, wn = wid & 1;               // 2x2 waves, each owns 64x64 of C

  // staging: thread covers granules tid (rows 0..63) and tid+256 (rows 64..127);
  // source col-slot s = (tid&3) ^ f(row), f(row)=(row>>1)&3 -> both granules same s
  int s = (tid & 3) ^ ((tid >> 3) & 3);
  const unsigned short* pA0 = A + (size_t)(row0 + (tid >> 2)) * KTOT + s * 8;
  const unsigned short* pA1 = pA0 + (size_t)64 * KTOT;
  const unsigned short* pB0 = Bp + (size_t)(n0 + (tid >> 2)) * KTOT + s * 8;
  const unsigned short* pB1 = pB0 + (size_t)64 * KTOT;
  int stL = wid * 512;                           // wave-uniform LDS base (shorts)

  // fragment reads: row = w*64 + i*16 + am, k-slot g=(lane>>4); swizzled slot = g^f(row)
  int am = lane & 15;
  int sF = ((lane >> 4) ^ ((lane >> 1) & 3)) * 8;
  int aoff = (wm * 64 + am) * 32 + sF;           // + i*512 per fragment
  int boff = 4096 + (wn * 64 + am) * 32 + sF;    // + j*512 per fragment

  f32x4 acc[4][4];
#pragma unroll
  for (int i = 0; i < 4; ++i)
#pragma unroll
    for (int j = 0; j < 4; ++j) acc[i][j] = (f32x4){0.f, 0.f, 0.f, 0.f};

  // prologue: stage tile 0 into buf 0
  gl16(pA0, lds + stL);          gl16(pA1, lds + stL + 2048);
  gl16(pB0, lds + 4096 + stL);   gl16(pB1, lds + 4096 + stL + 2048);
  FENCE();

  // main loop: iters 0..NKT-3 in 3-unrolled groups, then NKT-2 (CUR=0), NKT-1 (CUR=1)
  for (int t = 0; t < NKT - 2; t += 3) {
    ktile<0, true, false>(lds, (t + 1) * 32, pA0, pA1, pB0, pB1, stL, aoff, boff, acc);
    ktile<1, true, false>(lds, (t + 2) * 32, pA0, pA1, pB0, pB1, stL, aoff, boff, acc);
    ktile<2, true, false>(lds, (t + 3) * 32, pA0, pA1, pB0, pB1, stL, aoff, boff, acc);
  }
  ktile<0, true, false>(lds, (NKT - 1) * 32, pA0, pA1, pB0, pB1, stL, aoff, boff, acc);
  ktile<1, false, true>(lds, 0, pA0, pA1, pB0, pB1, stL, aoff, boff, acc);

  // epilogue.  C/D: col n = lane&15, row m = (lane>>4)*4 + reg
  int rbase = row0 + wm * 64 + ((lane >> 4) << 2);
  int nbase = n0 + wn * 64 + am;
  if constexpr (EPI == 0) {
    unsigned short* Hp = (unsigned short*)Cout;
    const float* bp = bias + (size_t)e * NTOT;
#pragma unroll
    for (int i = 0; i < 4; ++i)
#pragma unroll
      for (int j = 0; j < 4; ++j) {
        int n = nbase + j * 16;
        float bv = bp[n];
#pragma unroll
        for (int g = 0; g < 4; ++g) {
          int m = rbase + i * 16 + g;
          float v = acc[i][j][g] + bv;
          v = 0.5f * v * (1.f + erff(v * 0.70710678118654752f));   // exact gelu
          Hp[(size_t)m * NTOT + n] = f2bf(v);
        }
      }
  } else {
    float* Op = (float*)Cout;
    const float* bp = bias + (size_t)e * NTOT;
#pragma unroll
    for (int i = 0; i < 4; ++i)
#pragma unroll
      for (int g = 0; g < 4; ++g) {
        int m = rbase + i * 16 + g;
        float wt = wt_of_row[m];
        if (wt != 0.f) {                         // pad rows excluded (wt exactly 0)
          float* orow = Op + (size_t)tok_of_row[m] * DIM;
#pragma unroll
          for (int j = 0; j < 4; ++j) {
            int n = nbase + j * 16;
            atomicAdd(orow + n, (acc[i][j][g] + bp[n]) * wt);
          }
        }
      }
  }
}

extern "C" void kernel_launch(void* const* d_in, const int* in_sizes, int n_in,
                              void* d_out, int out_size, void* d_ws, size_t ws_size,
                              hipStream_t stream) {
  const float* x  = (const float*)d_in[0];
  const float* Wr = (const float*)d_in[1];
  const float* br = (const float*)d_in[2];
  const float* W1 = (const float*)d_in[3];
  const float* b1 = (const float*)d_in[4];
  const float* W2 = (const float*)d_in[5];
  const float* b2 = (const float*)d_in[6];
  float* out = (float*)d_out;

  char* base = (char*)d_ws;
  size_t off = 0;
  auto carve = [&](size_t bytes) -> void* {
    void* r = base + off;
    off = (off + bytes + 255) & ~(size_t)255;
    return r;
  };
  int*            meta       = (int*)carve(26 * 4);
  int2*           top_i      = (int2*)carve((size_t)T_TOK * 8);
  float2*         top_w      = (float2*)carve((size_t)T_TOK * 8);
  int*            row_of     = (int*)carve((size_t)T_TOK * 2 * 4);
  int*            tok_of_row = (int*)carve((size_t)MAXR * 4);
  float*          wt_of_row  = (float*)carve((size_t)MAXR * 4);
  unsigned short* xg         = (unsigned short*)carve((size_t)MAXR * DIM * 2);
  unsigned short* W1bT       = (unsigned short*)carve((size_t)NEXP * DIM * HID * 2);
  unsigned short* W2bT       = (unsigned short*)carve((size_t)NEXP * DIM * HID * 2);
  unsigned short* hbuf       = (unsigned short*)carve((size_t)MAXR * HID * 2);
  if (off > ws_size) {
    fprintf(stderr, "kernel_launch: ws_size too small: need %zu have %zu\n", off, ws_size);
    return;
  }

  hipMemsetAsync(meta, 0, 26 * 4, stream);
  hipMemsetAsync(out, 0, (size_t)out_size * 4, stream);   // GEMM2 atomicAdds into out
  hipLaunchKernelGGL(transpose_convert_k, dim3(HID / 32, DIM / 32, NEXP), dim3(256), 0, stream,
                     W1, W1bT, DIM, HID);                 // W1[e][D][H] -> [e][H][D]
  hipLaunchKernelGGL(transpose_convert_k, dim3(DIM / 32, HID / 32, NEXP), dim3(256), 0, stream,
                     W2, W2bT, HID, DIM);                 // W2[e][H][D] -> [e][D][H]
  hipLaunchKernelGGL(fill_k, dim3((MAXR + 255) / 256), dim3(256), 0, stream,
                     tok_of_row, wt_of_row);
  hipLaunchKernelGGL(router_k, dim3(T_TOK / 4), dim3(256), 0, stream,
                     x, Wr, br, meta, top_i, top_w);
  hipLaunchKernelGGL(prefix_k, dim3(1), dim3(64), 0, stream, meta);
  hipLaunchKernelGGL(scatter_k, dim3(T_TOK / 256), dim3(256), 0, stream,
                     top_i, top_w, meta, row_of, tok_of_row, wt_of_row);
  hipLaunchKernelGGL(gather_k, dim3(MAXR), dim3(256), 0, stream, x, tok_of_row, meta, xg);
  hipLaunchKernelGGL((gemm3_k<DIM, HID, 0>), dim3((MAXR / 128) * (HID / 128)), dim3(256), 0,
                     stream, xg, W1bT, b1, meta, wt_of_row, tok_of_row, (void*)hbuf);
  hipLaunchKernelGGL((gemm3_k<HID, DIM, 1>), dim3((MAXR / 128) * (DIM / 128)), dim3(256), 0,
                     stream, hbuf, W2bT, b2, meta, wt_of_row, tok_of_row, (void*)out);
}